// Round 6
// baseline (194.513 us; speedup 1.0000x reference)
//
#include <hip/hip_runtime.h>
#include <hip/hip_bf16.h>

// Causal SDPA: B=4, H=16, S=2048, D=64, fp32 in/out.
// R14 = barrier-FREE wave-private flash (evidence R8-R13: slot = L/W,
// latency-bound; no pipe >55%; per-kv DS/VALU/MFMA work identical here).
//   - 1 wave/block (64 thr), 32 q-rows, kv-tile 32. LDS/block = K dbuf 8K +
//     V 4K + P 4K = 16K -> 10 blocks/CU (W=10 free-running waves, was 5x2
//     lockstepped). Grid 4096, big-t first, XCD-pinned bh.
//   - ZERO __syncthreads. All sync is wave-local counted vmcnt:
//     top vmcnt(8) drains K(kt) [keeps V(kt)+K(kt+1) in flight],
//     pre-PV vmcnt(4) drains V(kt) [keeps K(kt+1)], diag peel uses 4/0.
//     lgkmcnt(0) before af reads (P roundtrip) and before DMA re-issue
//     (protects Vl/Kl reads vs overwrite). K(kt+2) reuses the buffer S^T
//     just consumed.
//   - R13 math unchanged: swapped S^T=K*Q^T, exp2 builtin, packed cvt +
//     f16 clamp, swizzled P roundtrip, ones-MFMA row-sum, O^T epilogue.
// Known accepted cost: V reads (64B rows) ~8-way bank conflict on 4
// reads/iter; SQ_LDS_BANK_CONFLICT will rise.

#define SEQ 2048
#define DIM 64
#define BH  64

typedef _Float16 half8  __attribute__((ext_vector_type(8)));
typedef _Float16 half4v __attribute__((ext_vector_type(4)));
typedef float    float4v __attribute__((ext_vector_type(4)));
typedef unsigned short ushort4v __attribute__((ext_vector_type(4)));

__device__ __forceinline__ void async16(const _Float16* g, _Float16* l) {
    __builtin_amdgcn_global_load_lds(
        (const __attribute__((address_space(1))) void*)g,
        (__attribute__((address_space(3))) void*)l, 16, 0, 0);
}

#if defined(__has_builtin)
#if __has_builtin(__builtin_elementwise_min)
#define EMIN4(a, b) __builtin_elementwise_min((a), (b))
#endif
#if __has_builtin(__builtin_amdgcn_exp2f)
#define EXP2F(x) __builtin_amdgcn_exp2f(x)
#endif
#endif
#ifndef EMIN4
__device__ __forceinline__ half4v emin4_fallback(half4v a, half4v b) {
    half4v r;
    r[0] = a[0] < b[0] ? a[0] : b[0];
    r[1] = a[1] < b[1] ? a[1] : b[1];
    r[2] = a[2] < b[2] ? a[2] : b[2];
    r[3] = a[3] < b[3] ? a[3] : b[3];
    return r;
}
#define EMIN4(a, b) emin4_fallback((a), (b))
#endif
#ifndef EXP2F
#define EXP2F(x) exp2f(x)
#endif

// ---------------- pre-pass: K convert + V transpose-convert ----------------
__global__ __launch_bounds__(256)
void prep_kernel(const float* __restrict__ K, const float* __restrict__ V,
                 _Float16* __restrict__ Kh, _Float16* __restrict__ Vt) {
    const int bid = blockIdx.x;
    const int tid = threadIdx.x;
    if (bid < 4096) {
        // K: fp32 -> f16, same layout, fully coalesced.
        size_t idx = (size_t)bid * 2048 + (size_t)tid * 8;
        float4v a = *(const float4v*)(K + idx);
        float4v b = *(const float4v*)(K + idx + 4);
        half8 h;
        h[0] = (_Float16)a[0]; h[1] = (_Float16)a[1];
        h[2] = (_Float16)a[2]; h[3] = (_Float16)a[3];
        h[4] = (_Float16)b[0]; h[5] = (_Float16)b[1];
        h[6] = (_Float16)b[2]; h[7] = (_Float16)b[3];
        *(half8*)(Kh + idx) = h;
    } else {
        // V transpose via LDS, flat [64 rows x 8 chunks of 16B].
        // Chunk c of row r stored at c ^ k(r), k(r) = (r + (r>>3)) & 7.
        __shared__ _Float16 Vl[64 * 64];
        const int b  = bid - 4096;
        const int bh = b >> 5;
        const int s0 = (b & 31) * 64;
        {
            const int r   = tid >> 2;         // s within tile
            const int c16 = (tid & 3) * 16;   // col group (d)
            const float* p = V + ((size_t)bh * SEQ + s0 + r) * DIM + c16;
            float4v x0 = *(const float4v*)(p);
            float4v x1 = *(const float4v*)(p + 4);
            float4v x2 = *(const float4v*)(p + 8);
            float4v x3 = *(const float4v*)(p + 12);
            half8 h0, h1;
            h0[0] = (_Float16)x0[0]; h0[1] = (_Float16)x0[1];
            h0[2] = (_Float16)x0[2]; h0[3] = (_Float16)x0[3];
            h0[4] = (_Float16)x1[0]; h0[5] = (_Float16)x1[1];
            h0[6] = (_Float16)x1[2]; h0[7] = (_Float16)x1[3];
            h1[0] = (_Float16)x2[0]; h1[1] = (_Float16)x2[1];
            h1[2] = (_Float16)x2[2]; h1[3] = (_Float16)x2[3];
            h1[4] = (_Float16)x3[0]; h1[5] = (_Float16)x3[1];
            h1[6] = (_Float16)x3[2]; h1[7] = (_Float16)x3[3];
            const int k  = (r + (r >> 3)) & 7;
            const int j0 = c16 >> 3;          // 0,2,4,6
            *(half8*)&Vl[r * 64 + ((j0    ) ^ k) * 8] = h0;
            *(half8*)&Vl[r * 64 + ((j0 + 1) ^ k) * 8] = h1;
        }
        __syncthreads();
        {
            const int d  = tid >> 2;          // output row (d)
            const int sc = (tid & 3) * 16;    // s chunk
            const int dh = d >> 3;            // chunk index of col d
            const int dl = d & 7;             // offset within chunk
            half8 o0, o1;
#pragma unroll
            for (int j = 0; j < 8; ++j) {
                const int s1 = sc + j;
                const int s2 = sc + 8 + j;
                o0[j] = Vl[s1 * 64 + ((dh ^ ((s1 + (s1 >> 3)) & 7)) << 3) + dl];
                o1[j] = Vl[s2 * 64 + ((dh ^ ((s2 + (s2 >> 3)) & 7)) << 3) + dl];
            }
            _Float16* op = Vt + ((size_t)bh * DIM + d) * SEQ + s0 + sc;
            *(half8*)op       = o0;
            *(half8*)(op + 8) = o1;
        }
    }
}

// ---------------- main flash kernel: 1 wave / 64 threads per block ----------
__global__ __launch_bounds__(64, 2)
void fa_main(const float* __restrict__ Q, const _Float16* __restrict__ Kh,
             const _Float16* __restrict__ Vt, float* __restrict__ O) {
    const int bid = blockIdx.x;
    // XCD swizzle: all 64 blocks of a bh on one XCD (K/V L2-resident:
    // 8 bh x 512KB = 4MB = one XCD L2). Big-t first for backfill packing.
    const int xcd = bid & 7;
    const int idx = bid >> 3;              // 0..511
    const int bh  = xcd * 8 + (idx & 7);
    const int t   = 63 - (idx >> 3);       // 32-row q-tile index, big first

    const float*    Qb = Q  + (size_t)bh * SEQ * DIM;
    const _Float16* Kb = Kh + (size_t)bh * SEQ * DIM;
    const _Float16* Vb = Vt + (size_t)bh * DIM * SEQ;
    float*          Ob = O  + (size_t)bh * SEQ * DIM;

    const int lane = threadIdx.x;          // 0..63 (one wave)
    const int row  = lane & 15;
    const int quad = lane >> 4;

    // LDS = 8K (K dbuf, 32x64) + 4K (V, 64x32) + 4K (P, 32x64) = 16384 B
    // -> 10 blocks/CU. ALL wave-private; no barriers anywhere.
    __shared__ _Float16 Kl[2][32 * 64];
    __shared__ _Float16 Vl[64 * 32];
    __shared__ _Float16 Pl[32 * 64];

    const float SC = 0.125f * 1.44269504f;   // 1/sqrt(D) * log2(e)
    const float4v z0 = {0.f, 0.f, 0.f, 0.f};
    half8 ones;
    {
        ushort4v ob;  // 0x3c00 = f16 1.0
        ob[0] = 0x3c00; ob[1] = 0x3c00; ob[2] = 0x3c00; ob[3] = 0x3c00;
        half4v o1 = __builtin_bit_cast(half4v, ob);
        ones[0] = o1[0]; ones[1] = o1[1]; ones[2] = o1[2]; ones[3] = o1[3];
        ones[4] = o1[0]; ones[5] = o1[1]; ones[6] = o1[2]; ones[7] = o1[3];
    }
    half4v wcap;
    {
        ushort4v cb2;  // 0x7400 = f16 16384.0 = 2^14
        cb2[0] = 0x7400; cb2[1] = 0x7400; cb2[2] = 0x7400; cb2[3] = 0x7400;
        wcap = __builtin_bit_cast(half4v, cb2);
    }

    // K tile 32x64 f16 = 256 x 16B chunks, 8 chunks/row, XOR-swizzled.
#define STAGE_K(bsel, kt_)                                                      \
    {                                                                           \
        const _Float16* Kt0 = Kb + (size_t)(kt_) * 32 * DIM;                    \
        _Pragma("unroll")                                                       \
        for (int i = 0; i < 4; ++i) {                                           \
            int pos = i * 64 + lane;                                            \
            int rr  = pos >> 3;                                                 \
            int cc  = (pos & 7) ^ (rr & 7);                                     \
            async16(Kt0 + (size_t)rr * DIM + cc * 8,                            \
                    &Kl[bsel][0] + (size_t)pos * 8);                            \
        }                                                                       \
    }
    // V tile (V^T rows d=0..63, 32 kv cols) = 256 x 16B, 4 chunks/row.
#define STAGE_V(kt_)                                                            \
    {                                                                           \
        const _Float16* Vt0 = Vb + (size_t)(kt_) * 32;                          \
        _Pragma("unroll")                                                       \
        for (int i = 0; i < 4; ++i) {                                           \
            int pos = i * 64 + lane;                                            \
            int rr  = pos >> 2;                                                 \
            int cc  = (pos & 3) ^ (rr & 3);                                     \
            async16(Vt0 + (size_t)rr * SEQ + cc * 8,                            \
                    &Vl[0] + (size_t)pos * 8);                                  \
        }                                                                       \
    }

    const int q0 = t * 32;

    // ---- Q fragments (scale folded; log2 domain)
    half8 qf[4];   // [qs*2 + s]
#pragma unroll
    for (int qs = 0; qs < 2; ++qs) {
        const float* qp = Qb + (size_t)(q0 + qs * 16 + row) * DIM;
#pragma unroll
        for (int s = 0; s < 2; ++s) {
            const float* p = qp + s * 32 + quad * 8;
            float4v a = *(const float4v*)p;
            float4v b = *(const float4v*)(p + 4);
            half8 h;
            h[0] = (_Float16)(a[0] * SC); h[1] = (_Float16)(a[1] * SC);
            h[2] = (_Float16)(a[2] * SC); h[3] = (_Float16)(a[3] * SC);
            h[4] = (_Float16)(b[0] * SC); h[5] = (_Float16)(b[1] * SC);
            h[6] = (_Float16)(b[2] * SC); h[7] = (_Float16)(b[3] * SC);
            qf[qs * 2 + s] = h;
        }
    }

    float4v o_acc[2][4];
    float4v lacc[2];
#pragma unroll
    for (int qs = 0; qs < 2; ++qs) {
        float4v z = {0.f, 0.f, 0.f, 0.f};
        lacc[qs] = z;
#pragma unroll
        for (int c = 0; c < 4; ++c) o_acc[qs][c] = z;
    }

    // ---- prologue: issue K(0), V(0), K(1). Invariant at iter kt top:
    //      outstanding (oldest->newest) = [K(kt), V(kt), K(kt+1)].
    STAGE_K(0, 0)
    STAGE_V(0)
    if (t >= 1) STAGE_K(1, 1)

    // ---- iteration body (DIAG selects waits 4/0 vs 8/4 and masking)
#define KV_ITER(kt_, DIAG, STV, STK)                                            \
    {                                                                           \
        const int cb = (kt_) & 1;                                               \
        if (DIAG) { asm volatile("s_waitcnt vmcnt(4)" ::: "memory"); }          \
        else      { asm volatile("s_waitcnt vmcnt(8)" ::: "memory"); }          \
        __builtin_amdgcn_sched_barrier(0);                                      \
        /* S^T = K * Q^T (kv-tile 32: c<2) */                                   \
        float4v sacc[2][2];                                                     \
        __builtin_amdgcn_s_setprio(1);                                          \
        _Pragma("unroll")                                                       \
        for (int c = 0; c < 2; ++c) {                                           \
            const int kv  = c * 16 + row;                                       \
            const int ch0 = quad ^ (kv & 7);                                    \
            const int ch1 = (4 + quad) ^ (kv & 7);                              \
            half8 kf0 = *(const half8*)&Kl[cb][kv * 64 + ch0 * 8];              \
            half8 kf1 = *(const half8*)&Kl[cb][kv * 64 + ch1 * 8];              \
            _Pragma("unroll")                                                   \
            for (int qs = 0; qs < 2; ++qs) {                                    \
                float4v s0 = __builtin_amdgcn_mfma_f32_16x16x32_f16(            \
                    kf0, qf[qs * 2 + 0], z0, 0, 0, 0);                          \
                sacc[qs][c] = __builtin_amdgcn_mfma_f32_16x16x32_f16(           \
                    kf1, qf[qs * 2 + 1], s0, 0, 0, 0);                          \
            }                                                                   \
        }                                                                       \
        __builtin_amdgcn_s_setprio(0);                                          \
        /* exp2 + pack + P write (swizzled 16B chunks) */                       \
        _Pragma("unroll")                                                       \
        for (int qs = 0; qs < 2; ++qs) {                                        \
            const int ql = qs * 16 + row;                                       \
            _Pragma("unroll")                                                   \
            for (int c = 0; c < 2; ++c) {                                       \
                float p0[4];                                                    \
                _Pragma("unroll")                                               \
                for (int rr = 0; rr < 4; ++rr) {                                \
                    float sx = sacc[qs][c][rr];                                 \
                    if (DIAG) {                                                 \
                        int kvl = c * 16 + quad * 4 + rr;                       \
                        sx = (kvl > ql) ? -1e30f : sx;                          \
                    }                                                           \
                    p0[rr] = EXP2F(sx);                                         \
                }                                                               \
                half4v w;                                                       \
                {                                                               \
                    auto t0_ = __builtin_amdgcn_cvt_pkrtz(p0[0], p0[1]);        \
                    auto t1_ = __builtin_amdgcn_cvt_pkrtz(p0[2], p0[3]);        \
                    w[0] = t0_[0]; w[1] = t0_[1]; w[2] = t1_[0]; w[3] = t1_[1]; \
                }                                                               \
                w = EMIN4(w, wcap);                                             \
                const int jc  = c * 2 + (quad >> 1);                            \
                const int col = ((jc ^ (row & 7)) << 3) + (quad & 1) * 4;       \
                *(half4v*)&Pl[(qs * 16 + row) * 64 + col] = w;                  \
            }                                                                   \
        }                                                                       \
        asm volatile("s_waitcnt lgkmcnt(0)" ::: "memory");                      \
        half8 af[2];                                                            \
        {                                                                       \
            const int js = quad ^ (row & 7);                                    \
            af[0] = *(const half8*)&Pl[(row) * 64 + js * 8];                    \
            af[1] = *(const half8*)&Pl[(16 + row) * 64 + js * 8];               \
        }                                                                       \
        /* V drain: keep K(kt+1) prefetch in flight in the main loop */         \
        if (DIAG) { asm volatile("s_waitcnt vmcnt(0)" ::: "memory"); }          \
        else      { asm volatile("s_waitcnt vmcnt(4)" ::: "memory"); }          \
        __builtin_amdgcn_sched_barrier(0);                                      \
        /* O^T += V^T * P^T ; l += ones * P^T */                                \
        __builtin_amdgcn_s_setprio(1);                                          \
        _Pragma("unroll")                                                       \
        for (int c = 0; c < 4; ++c) {                                           \
            const int d  = c * 16 + row;                                        \
            const int ch = quad ^ (d & 3);                                      \
            half8 vf = *(const half8*)&Vl[d * 32 + ch * 8];                     \
            o_acc[0][c] = __builtin_amdgcn_mfma_f32_16x16x32_f16(               \
                vf, af[0], o_acc[0][c], 0, 0, 0);                               \
            o_acc[1][c] = __builtin_amdgcn_mfma_f32_16x16x32_f16(               \
                vf, af[1], o_acc[1][c], 0, 0, 0);                               \
        }                                                                       \
        lacc[0] = __builtin_amdgcn_mfma_f32_16x16x32_f16(ones, af[0], lacc[0], 0, 0, 0); \
        lacc[1] = __builtin_amdgcn_mfma_f32_16x16x32_f16(ones, af[1], lacc[1], 0, 0, 0); \
        __builtin_amdgcn_s_setprio(0);                                          \
        if (!(DIAG)) {                                                          \
            /* all LDS reads must complete before DMA overwrites Vl/Kl[cb] */   \
            asm volatile("s_waitcnt lgkmcnt(0)" ::: "memory");                  \
            __builtin_amdgcn_sched_barrier(0);                                  \
            if (STV) STAGE_V((kt_) + 1)                                         \
            if (STK) STAGE_K(cb, (kt_) + 2)                                     \
        }                                                                       \
    }

    // ---- main loop (kt < t): no mask, waits 8/4, prefetch V(kt+1)/K(kt+2)
    for (int kt = 0; kt < t; ++kt) {
        KV_ITER(kt, false, true, (kt < t - 1))
    }
    // ---- peeled diagonal (kt = t): mask, waits 4/0, no staging
    KV_ITER(t, true, false, false)

    // ---- epilogue: every lane holds full l(q) in lacc[qs][0]
#pragma unroll
    for (int qs = 0; qs < 2; ++qs) {
        const float inv = 1.0f / lacc[qs][0];
        float* op = Ob + (size_t)(q0 + qs * 16 + row) * DIM + quad * 4;
#pragma unroll
        for (int c = 0; c < 4; ++c) {
            float4v o;
            o[0] = o_acc[qs][c][0] * inv; o[1] = o_acc[qs][c][1] * inv;
            o[2] = o_acc[qs][c][2] * inv; o[3] = o_acc[qs][c][3] * inv;
            *(float4v*)(op + c * 16) = o;
        }
    }
}

// ---------------- fallback (R1 kernel, used if ws too small) ----------------
__global__ __launch_bounds__(256)
void fa_causal_fallback(const float* __restrict__ Q, const float* __restrict__ K,
                        const float* __restrict__ V, float* __restrict__ O) {
    const int bid = blockIdx.x;
    const int bh  = bid >> 5;
    const int qt  = bid & 31;
    const int q0  = qt * 64;

    const float* Qb = Q + (size_t)bh * SEQ * DIM;
    const float* Kb = K + (size_t)bh * SEQ * DIM;
    const float* Vb = V + (size_t)bh * SEQ * DIM;
    float*       Ob = O + (size_t)bh * SEQ * DIM;

    const int tid  = threadIdx.x;
    const int wave = tid >> 6;
    const int lane = tid & 63;
    const int row  = lane & 15;
    const int quad = lane >> 4;

    __shared__ _Float16 Kl[64][72];
    __shared__ _Float16 Vt[64][72];
    __shared__ _Float16 Pl[4][16][72];

    half8 qf[2];
    {
        const float* qp = Qb + (size_t)(q0 + wave * 16 + row) * DIM;
#pragma unroll
        for (int s = 0; s < 2; ++s) {
            const float* p = qp + s * 32 + quad * 8;
            float4v a = *(const float4v*)p;
            float4v b = *(const float4v*)(p + 4);
            half8 h;
            h[0] = (_Float16)a[0]; h[1] = (_Float16)a[1];
            h[2] = (_Float16)a[2]; h[3] = (_Float16)a[3];
            h[4] = (_Float16)b[0]; h[5] = (_Float16)b[1];
            h[6] = (_Float16)b[2]; h[7] = (_Float16)b[3];
            qf[s] = h;
        }
    }

    float m_i[4] = {-1e30f, -1e30f, -1e30f, -1e30f};
    float l_i[4] = {0.f, 0.f, 0.f, 0.f};
    float4v o_acc[4];
#pragma unroll
    for (int c = 0; c < 4; ++c) { float4v z = {0.f, 0.f, 0.f, 0.f}; o_acc[c] = z; }

    const float LOG2E = 1.44269504f;

    for (int kt = 0; kt <= qt; ++kt) {
        __syncthreads();
        {
            const int kvr = tid >> 2;
            const int c4  = tid & 3;
            const float* kp = Kb + (size_t)(kt * 64 + kvr) * DIM + c4 * 16;
            const float* vp = Vb + (size_t)(kt * 64 + kvr) * DIM + c4 * 16;
#pragma unroll
            for (int i = 0; i < 4; ++i) {
                float4v kx = *(const float4v*)(kp + i * 4);
                float4v vx = *(const float4v*)(vp + i * 4);
#pragma unroll
                for (int j = 0; j < 4; ++j) {
                    Kl[kvr][c4 * 16 + i * 4 + j] = (_Float16)kx[j];
                    Vt[c4 * 16 + i * 4 + j][kvr] = (_Float16)vx[j];
                }
            }
        }
        __syncthreads();

        float4v sacc[4];
#pragma unroll
        for (int c = 0; c < 4; ++c) { float4v z = {0.f, 0.f, 0.f, 0.f}; sacc[c] = z; }
#pragma unroll
        for (int c = 0; c < 4; ++c)
#pragma unroll
            for (int s = 0; s < 2; ++s) {
                half8 kf = *(const half8*)&Kl[c * 16 + row][s * 32 + quad * 8];
                sacc[c] = __builtin_amdgcn_mfma_f32_16x16x32_f16(qf[s], kf, sacc[c], 0, 0, 0);
            }

        float sv[4][4];
        const bool diag = (kt == qt);
#pragma unroll
        for (int c = 0; c < 4; ++c)
#pragma unroll
            for (int r = 0; r < 4; ++r) {
                float v = sacc[c][r] * 0.125f;
                if (diag) {
                    int kvl = c * 16 + row;
                    int ql  = wave * 16 + quad * 4 + r;
                    if (kvl > ql) v = -1e30f;
                }
                sv[c][r] = v;
            }

        float mnew[4], alpha[4];
#pragma unroll
        for (int r = 0; r < 4; ++r) {
            float rm = fmaxf(fmaxf(sv[0][r], sv[1][r]), fmaxf(sv[2][r], sv[3][r]));
            rm = fmaxf(rm, __shfl_xor(rm, 1));
            rm = fmaxf(rm, __shfl_xor(rm, 2));
            rm = fmaxf(rm, __shfl_xor(rm, 4));
            rm = fmaxf(rm, __shfl_xor(rm, 8));
            mnew[r]  = fmaxf(m_i[r], rm);
            alpha[r] = exp2f((m_i[r] - mnew[r]) * LOG2E);
            m_i[r]   = mnew[r];
        }
        float rs[4] = {0.f, 0.f, 0.f, 0.f};
#pragma unroll
        for (int c = 0; c < 4; ++c)
#pragma unroll
            for (int r = 0; r < 4; ++r) {
                float p = exp2f((sv[c][r] - mnew[r]) * LOG2E);
                sv[c][r] = p;
                rs[r] += p;
            }
#pragma unroll
        for (int r = 0; r < 4; ++r) {
            float s = rs[r];
            s += __shfl_xor(s, 1);
            s += __shfl_xor(s, 2);
            s += __shfl_xor(s, 4);
            s += __shfl_xor(s, 8);
            l_i[r] = l_i[r] * alpha[r] + s;
        }
#pragma unroll
        for (int c = 0; c < 4; ++c)
#pragma unroll
            for (int r = 0; r < 4; ++r)
                o_acc[c][r] *= alpha[r];

#pragma unroll
        for (int c = 0; c < 4; ++c)
#pragma unroll
            for (int r = 0; r < 4; ++r)
                Pl[wave][quad * 4 + r][c * 16 + row] = (_Float16)sv[c][r];
        __syncthreads();

        half8 af[2];
#pragma unroll
        for (int s = 0; s < 2; ++s)
            af[s] = *(const half8*)&Pl[wave][row][s * 32 + quad * 8];
#pragma unroll
        for (int c = 0; c < 4; ++c)
#pragma unroll
            for (int s = 0; s < 2; ++s) {
                half8 vf = *(const half8*)&Vt[c * 16 + row][s * 32 + quad * 8];
                o_acc[c] = __builtin_amdgcn_mfma_f32_16x16x32_f16(af[s], vf, o_acc[c], 0, 0, 0);
            }
    }

#pragma unroll
    for (int r = 0; r < 4; ++r) {
        float inv = 1.0f / l_i[r];
        float* op = Ob + (size_t)(q0 + wave * 16 + quad * 4 + r) * DIM;
#pragma unroll
        for (int c = 0; c < 4; ++c)
            op[c * 16 + row] = o_acc[c][r] * inv;
    }
}

extern "C" void kernel_launch(void* const* d_in, const int* in_sizes, int n_in,
                              void* d_out, int out_size, void* d_ws, size_t ws_size,
                              hipStream_t stream) {
    const float* Q = (const float*)d_in[0];
    const float* K = (const float*)d_in[1];
    const float* V = (const float*)d_in[2];
    float* O = (float*)d_out;

    const size_t elems = (size_t)BH * SEQ * DIM;
    const size_t need  = 2 * elems * sizeof(_Float16);

    if (ws_size >= need) {
        _Float16* Kh = (_Float16*)d_ws;
        _Float16* Vt = Kh + elems;
        prep_kernel<<<4096 + 2048, 256, 0, stream>>>(K, V, Kh, Vt);
        fa_main<<<BH * 64, 64, 0, stream>>>(Q, Kh, Vt, O);
    } else {
        fa_causal_fallback<<<BH * 32, 256, 0, stream>>>(Q, K, V, O);
    }
}